// Round 8
// baseline (550.100 us; speedup 1.0000x reference)
//
#include <hip/hip_runtime.h>
#include <hip/hip_cooperative_groups.h>

namespace cg = cooperative_groups;

#define NB 8
#define NN 50000
#define NC 64
#define NE 400000

typedef unsigned short us4 __attribute__((ext_vector_type(4)));
typedef unsigned short us8 __attribute__((ext_vector_type(8)));
typedef short s8v __attribute__((ext_vector_type(8)));   // bf16x8 MFMA operand
typedef float f4v __attribute__((ext_vector_type(4)));   // fp32x4 MFMA acc / NT float4

__device__ __forceinline__ float bf2f(unsigned short u) {
  union { unsigned int i; float f; } v; v.i = ((unsigned int)u) << 16; return v.f;
}
__device__ __forceinline__ unsigned short f2bf(float f) {
  union { float f; unsigned int i; } v; v.f = f;
  unsigned int x = v.i;
  return (unsigned short)((x + 0x7FFFu + ((x >> 16) & 1u)) >> 16);  // RNE
}
__device__ __forceinline__ void fma4(float4& a, float s, const float4& v) {
  a.x = fmaf(s, v.x, a.x); a.y = fmaf(s, v.y, a.y);
  a.z = fmaf(s, v.z, a.z); a.w = fmaf(s, v.w, a.w);
}

// ---- full-record gather core -----------------------------------------------
__device__ __forceinline__ void gather_group(
    const unsigned short* __restrict__ tb, const int2* __restrict__ edges,
    int s, int e, int lane, int2 myed, float (&acc)[8]) {
  int jc = s;
  while (jc < e) {
    int take = e - jc; if (take > 64) take = 64;
    if (jc != s) myed = edges[jc + (lane < take ? lane : take - 1)];
    int full = take & ~7;
    int m = 0;
    for (; m < full; m += 8) {
      us8 v[8]; float lp[8];
#pragma unroll
      for (int u = 0; u < 8; ++u) {
        int c = __shfl(myed.x, m + u, 64);
        lp[u] = __int_as_float(__shfl(myed.y, m + u, 64));
        v[u] = *(const us8*)&tb[(size_t)c * 512];
      }
#pragma unroll
      for (int u = 0; u < 8; ++u)
#pragma unroll
        for (int q = 0; q < 8; ++q) acc[q] = fmaf(lp[u], bf2f(v[u][q]), acc[q]);
    }
    if (m < take) {                      // wave-uniform tail, rem in [1,7]
      int rem = take - m;
      us8 v[8]; float lp[8];
#pragma unroll
      for (int u = 0; u < 8; ++u) {
        if (u < rem) {
          int c = __shfl(myed.x, m + u, 64);
          lp[u] = __int_as_float(__shfl(myed.y, m + u, 64));
          v[u] = *(const us8*)&tb[(size_t)c * 512];
        }
      }
#pragma unroll
      for (int u = 0; u < 8; ++u) {
        if (u < rem) {
#pragma unroll
          for (int q = 0; q < 8; ++q) acc[q] = fmaf(lp[u], bf2f(v[u][q]), acc[q]);
        }
      }
    }
    jc += take;
  }
}

// ---- half-record gather core (batch-halved fused passes) -------------------
__device__ __forceinline__ void gather_group_h(
    const unsigned short* __restrict__ tbh, const int2* __restrict__ edges,
    int s, int e, int lane, int2 myed, float (&acc)[4]) {
  int jc = s;
  while (jc < e) {
    int take = e - jc; if (take > 64) take = 64;
    if (jc != s) myed = edges[jc + (lane < take ? lane : take - 1)];
    int full = take & ~7;
    int m = 0;
    for (; m < full; m += 8) {
      us4 v[8]; float lp[8];
#pragma unroll
      for (int u = 0; u < 8; ++u) {
        int c = __shfl(myed.x, m + u, 64);
        lp[u] = __int_as_float(__shfl(myed.y, m + u, 64));
        v[u] = *(const us4*)&tbh[(size_t)c * 512];
      }
#pragma unroll
      for (int u = 0; u < 8; ++u)
#pragma unroll
        for (int q = 0; q < 4; ++q) acc[q] = fmaf(lp[u], bf2f(v[u][q]), acc[q]);
    }
    if (m < take) {
      int rem = take - m;
      us4 v[8]; float lp[8];
#pragma unroll
      for (int u = 0; u < 8; ++u) {
        if (u < rem) {
          int c = __shfl(myed.x, m + u, 64);
          lp[u] = __int_as_float(__shfl(myed.y, m + u, 64));
          v[u] = *(const us4*)&tbh[(size_t)c * 512];
        }
      }
#pragma unroll
      for (int u = 0; u < 8; ++u) {
        if (u < rem) {
#pragma unroll
          for (int q = 0; q < 4; ++q) acc[q] = fmaf(lp[u], bf2f(v[u][q]), acc[q]);
        }
      }
    }
    jc += take;
  }
}

// ---- cooperative CSR build: count -> offsets -> scatter in ONE dispatch ----
// Tests the launch-overhead hypothesis (wall - kernel-sum ~ 22 us/dispatch).
// cnt[0..NN] is zeroed by cheb_pre (unchanged); grid.sync() orders phases.
// 1024 blocks x 256 (co-residency guaranteed by cooperative launch API).
__global__ __launch_bounds__(256) void cheb_csr(
    const int* __restrict__ ei, int* __restrict__ cnt, float* __restrict__ dinv,
    int* __restrict__ rowptr, int* __restrict__ cur) {
  cg::grid_group grid = cg::this_grid();
  int tid = blockIdx.x * blockDim.x + threadIdx.x;
  int nth = gridDim.x * blockDim.x;
  int* total = cnt + NN;

  // phase 1: degree count
  for (int e = tid; e < NE; e += nth) {
    int r = ei[e], c = ei[NE + e];
    if (r != c) atomicAdd(&cnt[r], 1);
  }
  grid.sync();

  // phase 2: offsets via wave scan + one atomic per wave (nth >= NN: 1 pass)
  {
    int lane = threadIdx.x & 63;
    if (tid - lane < NN) {               // wave-uniform skip of all-invalid waves
      bool valid = tid < NN;
      int c = valid ? cnt[tid] : 0;
      int inc = c;
#pragma unroll
      for (int d = 1; d < 64; d <<= 1) {
        int t = __shfl_up(inc, d, 64);
        if (lane >= d) inc += t;
      }
      int wtot = __shfl(inc, 63, 64);
      int base = 0;
      if (lane == 63) base = atomicAdd(total, wtot);
      base = __shfl(base, 63, 64);
      int s = base + inc - c;            // exclusive position (bucket order irrelevant)
      if (valid) {
        dinv[tid] = (c > 0) ? rsqrtf((float)c) : 0.0f;
        rowptr[tid] = s;
        cur[tid] = s;
      }
    }
  }
  grid.sync();

  // phase 3: scatter edges
  int2* edges = (int2*)(cur + NN);       // see alloc order: edges follows cur? NO - passed via param below
}

// NOTE: edges pointer passed explicitly; split kernel body above rewritten here
// (kept single definition - the real one):
__global__ __launch_bounds__(256) void cheb_csr2(
    const int* __restrict__ ei, int* __restrict__ cnt, float* __restrict__ dinv,
    int* __restrict__ rowptr, int* __restrict__ cur, int2* __restrict__ edges) {
  cg::grid_group grid = cg::this_grid();
  int tid = blockIdx.x * blockDim.x + threadIdx.x;
  int nth = gridDim.x * blockDim.x;
  int* total = cnt + NN;

  for (int e = tid; e < NE; e += nth) {
    int r = ei[e], c = ei[NE + e];
    if (r != c) atomicAdd(&cnt[r], 1);
  }
  grid.sync();

  {
    int lane = threadIdx.x & 63;
    if (tid - lane < NN) {
      bool valid = tid < NN;
      int c = valid ? cnt[tid] : 0;
      int inc = c;
#pragma unroll
      for (int d = 1; d < 64; d <<= 1) {
        int t = __shfl_up(inc, d, 64);
        if (lane >= d) inc += t;
      }
      int wtot = __shfl(inc, 63, 64);
      int base = 0;
      if (lane == 63) base = atomicAdd(total, wtot);
      base = __shfl(base, 63, 64);
      int s = base + inc - c;
      if (valid) {
        dinv[tid] = (c > 0) ? rsqrtf((float)c) : 0.0f;
        rowptr[tid] = s;
        cur[tid] = s;
      }
    }
  }
  grid.sync();

  for (int e = tid; e < NE; e += nth) {
    int r = ei[e], c = ei[NE + e];
    if (r == c) continue;
    int pos = atomicAdd(&cur[r], 1);
    float lap = -dinv[r] * dinv[c];
    edges[pos] = make_int2(c, __float_as_int(lap));
  }
}

// ---- classic CSR kernels (fallback tiers only) ------------------------------
__global__ void cheb_count(const int* __restrict__ ei, int* __restrict__ cnt) {
  int e = blockIdx.x * blockDim.x + threadIdx.x;
  if (e >= NE) return;
  int r = ei[e], c = ei[NE + e];
  if (r != c) atomicAdd(&cnt[r], 1);
}

__global__ void cheb_offsets(const int* __restrict__ cnt, float* __restrict__ dinv,
                             int* __restrict__ rowptr, int* __restrict__ cur,
                             int* __restrict__ total) {
  int n = blockIdx.x * blockDim.x + threadIdx.x;
  int lane = threadIdx.x & 63;
  bool valid = n < NN;
  int c = valid ? cnt[n] : 0;
  int inc = c;
#pragma unroll
  for (int d = 1; d < 64; d <<= 1) {
    int t = __shfl_up(inc, d, 64);
    if (lane >= d) inc += t;
  }
  int wtot = __shfl(inc, 63, 64);
  int base = 0;
  if (lane == 63) base = atomicAdd(total, wtot);
  base = __shfl(base, 63, 64);
  int s = base + inc - c;
  if (valid) {
    dinv[n] = (c > 0) ? rsqrtf((float)c) : 0.0f;
    rowptr[n] = s;
    cur[n] = s;
  }
}

__global__ void cheb_scatter(const int* __restrict__ ei, const float* __restrict__ dinv,
                             int* __restrict__ cur, int2* __restrict__ edges) {
  int e = blockIdx.x * blockDim.x + threadIdx.x;
  if (e >= NE) return;
  int r = ei[e], c = ei[NE + e];
  if (r == c) return;
  int pos = atomicAdd(&cur[r], 1);
  float lap = -dinv[r] * dinv[c];
  edges[pos] = make_int2(c, __float_as_int(lap));
}

// ---- Wc fp32 (fallback path only) ------------------------------------------
__global__ void cheb_wc(const float* __restrict__ w, float* __restrict__ wc) {
  int i = blockIdx.x * blockDim.x + threadIdx.x;
  if (i >= NC * NC) return;
  float w0 = w[i];
  float w1 = w[NC * NC + i];
  float w2 = w[2 * NC * NC + i];
  wc[i] = w0 - w2;
  wc[NC * NC + i] = w1;
  wc[2 * NC * NC + i] = 2.0f * w2;
}

// ---- pre kernel: {zero cnt/total} + {wpack} + {convert} in ONE dispatch -----
#define PRE_CONV_BLK 25000                       /* NN*128/256 exactly */
#define PRE_ZERO_BLK 196                         /* ceil((NN+1)/256)   */
__global__ __launch_bounds__(256) void cheb_pre(
    const float* __restrict__ x, unsigned short* __restrict__ xh,
    const float* __restrict__ w, unsigned short* __restrict__ pack,
    int* __restrict__ cnt) {
  int bid = blockIdx.x;
  if (bid < PRE_CONV_BLK) {
    int t = bid * 256 + threadIdx.x;
    int n = t >> 7;
    int rem = t & 127;
    int b = rem >> 4;
    int c4 = (rem & 15) * 4;
    f4v v = __builtin_nontemporal_load((const f4v*)&x[((size_t)b * NN + n) * 64 + c4]);
    us4 o;
    o[0] = f2bf(v[0]); o[1] = f2bf(v[1]); o[2] = f2bf(v[2]); o[3] = f2bf(v[3]);
    *(us4*)&xh[(size_t)n * 512 + b * 64 + c4] = o;
  } else if (bid < PRE_CONV_BLK + PRE_ZERO_BLK) {
    int i = (bid - PRE_CONV_BLK) * 256 + threadIdx.x;
    if (i <= NN) cnt[i] = 0;                     // includes total slot at cnt[NN]
  } else {
    // pack[(((ks*4+nt)*64)+l)*8+jj] = Wc[ks*32+(l>>4)*8+jj][nt*16+(l&15)]
    int t = (bid - PRE_CONV_BLK - PRE_ZERO_BLK) * 256 + threadIdx.x;
    if (t >= 6 * 4 * 64 * 8) return;
    int jj = t & 7;
    int l  = (t >> 3) & 63;
    int nt = (t >> 9) & 3;
    int ks = t >> 11;
    int k = ks * 32 + ((l >> 4) * 8) + jj;     // 0..191
    int o = nt * 16 + (l & 15);                // 0..63
    int ki = k & 63, ch = k >> 6;
    float v;
    if (ch == 0)      v = w[ki * 64 + o] - w[2 * 4096 + ki * 64 + o];
    else if (ch == 1) v = w[4096 + ki * 64 + o];
    else              v = 2.0f * w[2 * 4096 + ki * 64 + o];
    pack[t] = f2bf(v);
  }
}

// ---- prop1h: tx1h[n] = sum lap * xh[col]; one wave per node (control) ------
__global__ __launch_bounds__(256) void cheb_prop1h(
    const unsigned short* __restrict__ tin, unsigned short* __restrict__ tout,
    const int* __restrict__ rowptr, const int* __restrict__ cnt,
    const int2* __restrict__ edges) {
  int n = (blockIdx.x << 2) + (threadIdx.x >> 6);
  if (n >= NN) return;
  int lane = threadIdx.x & 63;
  int s = rowptr[n], c = cnt[n];
  const unsigned short* tb = tin + lane * 8;
  float acc[8];
#pragma unroll
  for (int q = 0; q < 8; ++q) acc[q] = 0.0f;
  if (c > 0) {
    int t0 = c > 64 ? 64 : c;
    int2 myed = edges[s + (lane < t0 ? lane : t0 - 1)];
    gather_group(tb, edges, s, s + c, lane, myed, acc);
  }
  us8 o;
#pragma unroll
  for (int q = 0; q < 8; ++q) o[q] = f2bf(acc[q]);
  *(us8*)&tout[(size_t)n * 512 + lane * 8] = o;
}

// ---- batch-halved fused prop2 + MFMA GEMM (unchanged from R7) ---------------
template <int PASS>
__global__ __launch_bounds__(256) void cheb_fusedh(
    const unsigned short* __restrict__ xh, const unsigned short* __restrict__ tx1h,
    const int* __restrict__ rowptr, const int* __restrict__ cnt,
    const int2* __restrict__ edges, const unsigned short* __restrict__ pack,
    const float* __restrict__ bias, float* __restrict__ out) {
  __shared__ unsigned short Pb[4][16][72];   // 16 rows x 144B, wave-private
  int w = threadIdx.x >> 6, lane = threadIdx.x & 63;
  int n0 = blockIdx.x * 16 + w * 4;          // 4 nodes per wave
  unsigned short (*P)[72] = Pb[w];

  int sj[4], cj[4];
#pragma unroll
  for (int j = 0; j < 4; ++j) { sj[j] = rowptr[n0 + j]; cj[j] = cnt[n0 + j]; }
  int2 med[4];
#pragma unroll
  for (int j = 0; j < 4; ++j) {
    int t0 = cj[j] > 64 ? 64 : cj[j];
    int idx = (t0 > 0) ? (sj[j] + (lane < t0 ? lane : t0 - 1)) : 0;
    med[j] = edges[idx];
  }

  const unsigned short* tbh = tx1h + PASS * 256 + lane * 4;
  for (int j = 0; j < 4; ++j) {
    float acc4[4];
#pragma unroll
    for (int q = 0; q < 4; ++q) acc4[q] = 0.0f;
    if (cj[j] > 0)
      gather_group_h(tbh, edges, sj[j], sj[j] + cj[j], lane, med[j], acc4);
    us4 o;
#pragma unroll
    for (int q = 0; q < 4; ++q) o[q] = f2bf(acc4[q]);
    *(us4*)&P[j * 4 + (lane >> 4)][(lane & 15) * 4] = o;
  }

  f4v acc[4];
#pragma unroll
  for (int nt = 0; nt < 4; ++nt) acc[nt] = (f4v){0.f, 0.f, 0.f, 0.f};

  int am = lane & 15, aq = (lane >> 4) * 8;
  int an = n0 + (am >> 2);
  int ab = PASS * 4 + (am & 3);
#pragma unroll
  for (int ks = 0; ks < 6; ++ks) {
    s8v a0;
    if (ks < 2) {
      a0 = __builtin_nontemporal_load(
          (const s8v*)&xh[(size_t)an * 512 + ab * 64 + ks * 32 + aq]);
    } else if (ks < 4) {
      a0 = *(const s8v*)&tx1h[(size_t)an * 512 + ab * 64 + (ks - 2) * 32 + aq];
    } else {
      a0 = *(const s8v*)&P[am][(ks - 4) * 32 + aq];
    }
#pragma unroll
    for (int nt = 0; nt < 4; ++nt) {
      s8v b = *(const s8v*)&pack[(((size_t)(ks * 4 + nt) * 64) + lane) * 8];
      acc[nt] = __builtin_amdgcn_mfma_f32_16x16x32_bf16(a0, b, acc[nt], 0, 0, 0);
    }
  }

  float bv[4];
#pragma unroll
  for (int nt = 0; nt < 4; ++nt) bv[nt] = bias[nt * 16 + (lane & 15)];
#pragma unroll
  for (int r = 0; r < 4; ++r) {
    int rl = (lane >> 4) * 4 + r;
    int n = n0 + (rl >> 2);
    int b = PASS * 4 + (rl & 3);
    float* orow = &out[((size_t)b * NN + n) * 64 + (lane & 15)];
#pragma unroll
    for (int nt = 0; nt < 4; ++nt)
      __builtin_nontemporal_store(acc[nt][r] + bv[nt], &orow[nt * 16]);
  }
}

// ---- fallback fp32 kernels (small-ws tiers) --------------------------------
__global__ __launch_bounds__(256) void cheb_prop(
    const float* __restrict__ tin, float* __restrict__ tout,
    const int* __restrict__ rowptr, const int* __restrict__ cnt,
    const int2* __restrict__ edges, int nwaves) {
  int wid = (blockIdx.x << 2) + (threadIdx.x >> 6);
  if (wid >= nwaves) return;
  int lane = threadIdx.x & 63;
  int b = wid / NN;
  int n = wid - b * NN;
  int s = rowptr[n];
  int e = s + cnt[n];
  const float* base = tin + (size_t)b * NN * NC;
  float acc = 0.0f;
  for (int j = s; j < e; ++j) {
    int2 ed = edges[j];
    acc += __int_as_float(ed.y) * base[(size_t)ed.x * NC + lane];
  }
  tout[((size_t)b * NN + n) * NC + lane] = acc;
}

__global__ __launch_bounds__(256) void cheb_gemm2(
    const float* __restrict__ x, const float* __restrict__ tx1,
    const float* ptx1, const float* __restrict__ wc,
    const float* __restrict__ bias, float* out, int nrows) {
  __shared__ float At[128][64];
  __shared__ float Ws[64][64];
  int tid = threadIdx.x;
  int tx = tid & 15;
  int ty = tid >> 4;
  long row0 = (long)blockIdx.x * 128;
  int sk4 = (tid & 15) * 4;
  int srb = tid >> 4;
  const float* sp[3] = {x, tx1, ptx1};
  float4 pa[8], pw[4];
  auto fetch = [&](int ch) {
    const float* s0 = sp[ch];
#pragma unroll
    for (int rr = 0; rr < 8; ++rr) {
      int roff = srb + rr * 16;
      if (row0 + roff < nrows)
        pa[rr] = *(const float4*)&s0[(size_t)(row0 + roff) * NC + sk4];
      else
        pa[rr] = make_float4(0.f, 0.f, 0.f, 0.f);
    }
#pragma unroll
    for (int ww = 0; ww < 4; ++ww) {
      int e4 = tid + 256 * ww;
      pw[ww] = *(const float4*)&wc[ch * 4096 + (e4 >> 4) * 64 + (e4 & 15) * 4];
    }
  };
  auto commit = [&]() {
#pragma unroll
    for (int rr = 0; rr < 8; ++rr)
      *(float4*)&At[srb + rr * 16][sk4] = pa[rr];
#pragma unroll
    for (int ww = 0; ww < 4; ++ww) {
      int e4 = tid + 256 * ww;
      *(float4*)&Ws[e4 >> 4][(e4 & 15) * 4] = pw[ww];
    }
  };
  float4 acc[8];
#pragma unroll
  for (int i = 0; i < 8; ++i) acc[i] = make_float4(0.f, 0.f, 0.f, 0.f);
  fetch(0);
  commit();
  for (int ch = 0; ch < 3; ++ch) {
    __syncthreads();
    if (ch < 2) fetch(ch + 1);
#pragma unroll 4
    for (int k4 = 0; k4 < 16; ++k4) {
      float4 w0 = *(float4*)&Ws[k4 * 4 + 0][tx * 4];
      float4 w1 = *(float4*)&Ws[k4 * 4 + 1][tx * 4];
      float4 w2 = *(float4*)&Ws[k4 * 4 + 2][tx * 4];
      float4 w3 = *(float4*)&Ws[k4 * 4 + 3][tx * 4];
#pragma unroll
      for (int i = 0; i < 8; ++i) {
        float4 a = *(float4*)&At[ty * 8 + i][k4 * 4];
        fma4(acc[i], a.x, w0);
        fma4(acc[i], a.y, w1);
        fma4(acc[i], a.z, w2);
        fma4(acc[i], a.w, w3);
      }
    }
    __syncthreads();
    if (ch < 2) commit();
  }
  float4 bb4 = *(const float4*)&bias[tx * 4];
#pragma unroll
  for (int i = 0; i < 8; ++i) {
    long r = row0 + ty * 8 + i;
    if (r >= nrows) continue;
    float4 o = make_float4(acc[i].x + bb4.x, acc[i].y + bb4.y,
                           acc[i].z + bb4.z, acc[i].w + bb4.w);
    *(float4*)&out[(size_t)r * NC + tx * 4] = o;
  }
}

extern "C" void kernel_launch(void* const* d_in, const int* in_sizes, int n_in,
                              void* d_out, int out_size, void* d_ws, size_t ws_size,
                              hipStream_t stream) {
  (void)in_sizes; (void)n_in; (void)out_size;
  const float* x    = (const float*)d_in[0];
  const float* w    = (const float*)d_in[1];
  const float* bias = (const float*)d_in[2];
  const int*   ei   = (const int*)d_in[3];
  float* out = (float*)d_out;
  char* ws = (char*)d_ws;

  size_t off = 0;
  auto alloc = [&](size_t bytes) -> void* {
    void* p = (void*)(ws + off);
    off = (off + bytes + 255) & ~(size_t)255;
    return p;
  };
  int* cnt      = (int*)alloc((size_t)(NN + 1) * sizeof(int));
  int* total    = cnt + NN;
  int* rowptr   = (int*)alloc((size_t)NN * sizeof(int));
  int* cur      = (int*)alloc((size_t)NN * sizeof(int));
  float* dinv   = (float*)alloc((size_t)NN * sizeof(float));
  int2* edges   = (int2*)alloc((size_t)NE * sizeof(int2));
  float* wcb    = (float*)alloc((size_t)3 * NC * NC * sizeof(float));
  unsigned short* pack = (unsigned short*)alloc((size_t)6 * 4 * 64 * 8 * sizeof(unsigned short));
  size_t small_end = off;

  const size_t fieldHB = (size_t)NN * 512 * sizeof(unsigned short);  // 51.2 MB
  const size_t perbB   = (size_t)NN * NC * sizeof(float);            // 12.8 MB

  if (ws_size >= small_end + 2 * fieldHB + 256) {
    // Tier A: bf16 pipeline; 5 dispatches (pre, coop CSR, prop1h, fusedh x2)
    unsigned short* xh   = (unsigned short*)alloc(fieldHB);
    unsigned short* tx1h = (unsigned short*)alloc(fieldHB);
    cheb_pre<<<PRE_CONV_BLK + PRE_ZERO_BLK + 48, 256, 0, stream>>>(
        x, xh, w, pack, cnt);
    {
      void* cargs[] = {(void*)&ei, (void*)&cnt, (void*)&dinv,
                       (void*)&rowptr, (void*)&cur, (void*)&edges};
      hipLaunchCooperativeKernel((const void*)cheb_csr2, dim3(1024), dim3(256),
                                 cargs, 0, stream);
    }
    cheb_prop1h <<<NN / 4, 256, 0, stream>>>(xh, tx1h, rowptr, cnt, edges);
    cheb_fusedh<0><<<NN / 16, 256, 0, stream>>>(
        xh, tx1h, rowptr, cnt, edges, pack, bias, out);
    cheb_fusedh<1><<<NN / 16, 256, 0, stream>>>(
        xh, tx1h, rowptr, cnt, edges, pack, bias, out);
  } else if (ws_size >= small_end + 2 * perbB + 256) {
    // Tier B: per-batch fp32 fallback (classic CSR path)
    hipMemsetAsync(cnt, 0, (NN + 1) * sizeof(int), stream);
    cheb_count  <<<(NE + 255) / 256, 256, 0, stream>>>(ei, cnt);
    cheb_offsets<<<(NN + 255) / 256, 256, 0, stream>>>(cnt, dinv, rowptr, cur, total);
    cheb_scatter<<<(NE + 255) / 256, 256, 0, stream>>>(ei, dinv, cur, edges);
    cheb_wc<<<(NC * NC + 255) / 256, 256, 0, stream>>>(w, wcb);
    float* tx1b  = (float*)alloc(perbB);
    float* ptx1b = (float*)alloc(perbB);
    for (int b = 0; b < NB; ++b) {
      const float* xb = x + (size_t)b * NN * NC;
      float* outb = out + (size_t)b * NN * NC;
      cheb_prop<<<(NN + 3) / 4, 256, 0, stream>>>(xb, tx1b, rowptr, cnt, edges, NN);
      cheb_prop<<<(NN + 3) / 4, 256, 0, stream>>>(tx1b, ptx1b, rowptr, cnt, edges, NN);
      cheb_gemm2<<<(NN + 127) / 128, 256, 0, stream>>>(
          xb, tx1b, ptx1b, wcb, bias, outb, NN);
    }
  } else {
    // Tier C: per-batch fp32, ptx1 via out slice
    hipMemsetAsync(cnt, 0, (NN + 1) * sizeof(int), stream);
    cheb_count  <<<(NE + 255) / 256, 256, 0, stream>>>(ei, cnt);
    cheb_offsets<<<(NN + 255) / 256, 256, 0, stream>>>(cnt, dinv, rowptr, cur, total);
    cheb_scatter<<<(NE + 255) / 256, 256, 0, stream>>>(ei, dinv, cur, edges);
    cheb_wc<<<(NC * NC + 255) / 256, 256, 0, stream>>>(w, wcb);
    float* tx1b = (float*)alloc(perbB);
    for (int b = 0; b < NB; ++b) {
      const float* xb = x + (size_t)b * NN * NC;
      float* outb = out + (size_t)b * NN * NC;
      cheb_prop<<<(NN + 3) / 4, 256, 0, stream>>>(xb, tx1b, rowptr, cnt, edges, NN);
      cheb_prop<<<(NN + 3) / 4, 256, 0, stream>>>(tx1b, outb, rowptr, cnt, edges, NN);
      cheb_gemm2<<<(NN + 127) / 128, 256, 0, stream>>>(
          xb, tx1b, outb, wcb, bias, outb, NN);
    }
  }
}

// Round 9
// 369.954 us; speedup vs baseline: 1.4869x; 1.4869x over previous
//
#include <hip/hip_runtime.h>

#define NB 8
#define NN 50000
#define NC 64
#define NE 400000

typedef unsigned short us4 __attribute__((ext_vector_type(4)));
typedef unsigned short us8 __attribute__((ext_vector_type(8)));
typedef short s8v __attribute__((ext_vector_type(8)));   // bf16x8 MFMA operand
typedef float f4v __attribute__((ext_vector_type(4)));   // fp32x4 MFMA acc / NT float4

__device__ __forceinline__ float bf2f(unsigned short u) {
  union { unsigned int i; float f; } v; v.i = ((unsigned int)u) << 16; return v.f;
}
__device__ __forceinline__ unsigned short f2bf(float f) {
  union { float f; unsigned int i; } v; v.f = f;
  unsigned int x = v.i;
  return (unsigned short)((x + 0x7FFFu + ((x >> 16) & 1u)) >> 16);  // RNE
}
__device__ __forceinline__ void fma4(float4& a, float s, const float4& v) {
  a.x = fmaf(s, v.x, a.x); a.y = fmaf(s, v.y, a.y);
  a.z = fmaf(s, v.z, a.z); a.w = fmaf(s, v.w, a.w);
}

// ---- full-record gather core -----------------------------------------------
// Measured invariant (R5/R6/R7/R8): gather kernels run at ~3.8-4.0 TB/s
// beyond-L2 service rate regardless of structure; gathers are contiguous
// 1KB/wave (zero waste). Keep the low-VGPR serial form.
__device__ __forceinline__ void gather_group(
    const unsigned short* __restrict__ tb, const int2* __restrict__ edges,
    int s, int e, int lane, int2 myed, float (&acc)[8]) {
  int jc = s;
  while (jc < e) {
    int take = e - jc; if (take > 64) take = 64;
    if (jc != s) myed = edges[jc + (lane < take ? lane : take - 1)];
    int full = take & ~7;
    int m = 0;
    for (; m < full; m += 8) {
      us8 v[8]; float lp[8];
#pragma unroll
      for (int u = 0; u < 8; ++u) {
        int c = __shfl(myed.x, m + u, 64);
        lp[u] = __int_as_float(__shfl(myed.y, m + u, 64));
        v[u] = *(const us8*)&tb[(size_t)c * 512];
      }
#pragma unroll
      for (int u = 0; u < 8; ++u)
#pragma unroll
        for (int q = 0; q < 8; ++q) acc[q] = fmaf(lp[u], bf2f(v[u][q]), acc[q]);
    }
    if (m < take) {                      // wave-uniform tail, rem in [1,7]
      int rem = take - m;
      us8 v[8]; float lp[8];
#pragma unroll
      for (int u = 0; u < 8; ++u) {
        if (u < rem) {
          int c = __shfl(myed.x, m + u, 64);
          lp[u] = __int_as_float(__shfl(myed.y, m + u, 64));
          v[u] = *(const us8*)&tb[(size_t)c * 512];
        }
      }
#pragma unroll
      for (int u = 0; u < 8; ++u) {
        if (u < rem) {
#pragma unroll
          for (int q = 0; q < 8; ++q) acc[q] = fmaf(lp[u], bf2f(v[u][q]), acc[q]);
        }
      }
    }
    jc += take;
  }
}

// ---- half-record gather core (batch-halved fused passes) -------------------
__device__ __forceinline__ void gather_group_h(
    const unsigned short* __restrict__ tbh, const int2* __restrict__ edges,
    int s, int e, int lane, int2 myed, float (&acc)[4]) {
  int jc = s;
  while (jc < e) {
    int take = e - jc; if (take > 64) take = 64;
    if (jc != s) myed = edges[jc + (lane < take ? lane : take - 1)];
    int full = take & ~7;
    int m = 0;
    for (; m < full; m += 8) {
      us4 v[8]; float lp[8];
#pragma unroll
      for (int u = 0; u < 8; ++u) {
        int c = __shfl(myed.x, m + u, 64);
        lp[u] = __int_as_float(__shfl(myed.y, m + u, 64));
        v[u] = *(const us4*)&tbh[(size_t)c * 512];
      }
#pragma unroll
      for (int u = 0; u < 8; ++u)
#pragma unroll
        for (int q = 0; q < 4; ++q) acc[q] = fmaf(lp[u], bf2f(v[u][q]), acc[q]);
    }
    if (m < take) {
      int rem = take - m;
      us4 v[8]; float lp[8];
#pragma unroll
      for (int u = 0; u < 8; ++u) {
        if (u < rem) {
          int c = __shfl(myed.x, m + u, 64);
          lp[u] = __int_as_float(__shfl(myed.y, m + u, 64));
          v[u] = *(const us4*)&tbh[(size_t)c * 512];
        }
      }
#pragma unroll
      for (int u = 0; u < 8; ++u) {
        if (u < rem) {
#pragma unroll
          for (int q = 0; q < 4; ++q) acc[q] = fmaf(lp[u], bf2f(v[u][q]), acc[q]);
        }
      }
    }
    jc += take;
  }
}

// ---- CSR build (classic 3-kernel path; coop grid.sync costs ~100us/sync,
//      measured R8: 217us vs 24us -> cooperative fusion refuted) -------------
__global__ void cheb_count(const int* __restrict__ ei, int* __restrict__ cnt) {
  int e = blockIdx.x * blockDim.x + threadIdx.x;
  if (e >= NE) return;
  int r = ei[e], c = ei[NE + e];
  if (r != c) atomicAdd(&cnt[r], 1);
}

__global__ void cheb_offsets(const int* __restrict__ cnt, float* __restrict__ dinv,
                             int* __restrict__ rowptr, int* __restrict__ cur,
                             int* __restrict__ total) {
  int n = blockIdx.x * blockDim.x + threadIdx.x;
  int lane = threadIdx.x & 63;
  bool valid = n < NN;
  int c = valid ? cnt[n] : 0;
  int inc = c;
#pragma unroll
  for (int d = 1; d < 64; d <<= 1) {
    int t = __shfl_up(inc, d, 64);
    if (lane >= d) inc += t;
  }
  int wtot = __shfl(inc, 63, 64);
  int base = 0;
  if (lane == 63) base = atomicAdd(total, wtot);
  base = __shfl(base, 63, 64);
  int s = base + inc - c;   // exclusive position (bucket order irrelevant)
  if (valid) {
    dinv[n] = (c > 0) ? rsqrtf((float)c) : 0.0f;
    rowptr[n] = s;
    cur[n] = s;
  }
}

__global__ void cheb_scatter(const int* __restrict__ ei, const float* __restrict__ dinv,
                             int* __restrict__ cur, int2* __restrict__ edges) {
  int e = blockIdx.x * blockDim.x + threadIdx.x;
  if (e >= NE) return;
  int r = ei[e], c = ei[NE + e];
  if (r == c) return;
  int pos = atomicAdd(&cur[r], 1);
  float lap = -dinv[r] * dinv[c];
  edges[pos] = make_int2(c, __float_as_int(lap));
}

// ---- Wc fp32 (fallback path only) ------------------------------------------
__global__ void cheb_wc(const float* __restrict__ w, float* __restrict__ wc) {
  int i = blockIdx.x * blockDim.x + threadIdx.x;
  if (i >= NC * NC) return;
  float w0 = w[i];
  float w1 = w[NC * NC + i];
  float w2 = w[2 * NC * NC + i];
  wc[i] = w0 - w2;
  wc[NC * NC + i] = w1;
  wc[2 * NC * NC + i] = 2.0f * w2;
}

// ---- pre kernel: {zero cnt/total} + {wpack} + {convert} in ONE dispatch -----
#define PRE_CONV_BLK 25000                       /* NN*128/256 exactly */
#define PRE_ZERO_BLK 196                         /* ceil((NN+1)/256)   */
__global__ __launch_bounds__(256) void cheb_pre(
    const float* __restrict__ x, unsigned short* __restrict__ xh,
    const float* __restrict__ w, unsigned short* __restrict__ pack,
    int* __restrict__ cnt) {
  int bid = blockIdx.x;
  if (bid < PRE_CONV_BLK) {
    // convert x (bnc fp32) -> xh (nbc bf16; node record = 1KB contiguous)
    int t = bid * 256 + threadIdx.x;
    int n = t >> 7;
    int rem = t & 127;
    int b = rem >> 4;
    int c4 = (rem & 15) * 4;
    f4v v = __builtin_nontemporal_load((const f4v*)&x[((size_t)b * NN + n) * 64 + c4]);
    us4 o;
    o[0] = f2bf(v[0]); o[1] = f2bf(v[1]); o[2] = f2bf(v[2]); o[3] = f2bf(v[3]);
    *(us4*)&xh[(size_t)n * 512 + b * 64 + c4] = o;
  } else if (bid < PRE_CONV_BLK + PRE_ZERO_BLK) {
    int i = (bid - PRE_CONV_BLK) * 256 + threadIdx.x;
    if (i <= NN) cnt[i] = 0;                     // includes total slot at cnt[NN]
  } else {
    // pack[(((ks*4+nt)*64)+l)*8+jj] = Wc[ks*32+(l>>4)*8+jj][nt*16+(l&15)]
    int t = (bid - PRE_CONV_BLK - PRE_ZERO_BLK) * 256 + threadIdx.x;
    if (t >= 6 * 4 * 64 * 8) return;
    int jj = t & 7;
    int l  = (t >> 3) & 63;
    int nt = (t >> 9) & 3;
    int ks = t >> 11;
    int k = ks * 32 + ((l >> 4) * 8) + jj;     // 0..191
    int o = nt * 16 + (l & 15);                // 0..63
    int ki = k & 63, ch = k >> 6;
    float v;
    if (ch == 0)      v = w[ki * 64 + o] - w[2 * 4096 + ki * 64 + o];
    else if (ch == 1) v = w[4096 + ki * 64 + o];
    else              v = 2.0f * w[2 * 4096 + ki * 64 + o];
    pack[t] = f2bf(v);
  }
}

// ---- prop1h: tx1h[n] = sum lap * xh[col]; one wave per node ----------------
__global__ __launch_bounds__(256) void cheb_prop1h(
    const unsigned short* __restrict__ tin, unsigned short* __restrict__ tout,
    const int* __restrict__ rowptr, const int* __restrict__ cnt,
    const int2* __restrict__ edges) {
  int n = (blockIdx.x << 2) + (threadIdx.x >> 6);
  if (n >= NN) return;
  int lane = threadIdx.x & 63;
  int s = rowptr[n], c = cnt[n];
  const unsigned short* tb = tin + lane * 8;
  float acc[8];
#pragma unroll
  for (int q = 0; q < 8; ++q) acc[q] = 0.0f;
  if (c > 0) {
    int t0 = c > 64 ? 64 : c;
    int2 myed = edges[s + (lane < t0 ? lane : t0 - 1)];
    gather_group(tb, edges, s, s + c, lane, myed, acc);
  }
  us8 o;
#pragma unroll
  for (int q = 0; q < 8; ++q) o[q] = f2bf(acc[q]);
  *(us8*)&tout[(size_t)n * 512 + lane * 8] = o;
}

// ---- batch-halved fused prop2 + MFMA GEMM ----------------------------------
template <int PASS>
__global__ __launch_bounds__(256) void cheb_fusedh(
    const unsigned short* __restrict__ xh, const unsigned short* __restrict__ tx1h,
    const int* __restrict__ rowptr, const int* __restrict__ cnt,
    const int2* __restrict__ edges, const unsigned short* __restrict__ pack,
    const float* __restrict__ bias, float* __restrict__ out) {
  __shared__ unsigned short Pb[4][16][72];   // 16 rows x 144B, wave-private
  int w = threadIdx.x >> 6, lane = threadIdx.x & 63;
  int n0 = blockIdx.x * 16 + w * 4;          // 4 nodes per wave
  unsigned short (*P)[72] = Pb[w];

  int sj[4], cj[4];
#pragma unroll
  for (int j = 0; j < 4; ++j) { sj[j] = rowptr[n0 + j]; cj[j] = cnt[n0 + j]; }
  int2 med[4];
#pragma unroll
  for (int j = 0; j < 4; ++j) {
    int t0 = cj[j] > 64 ? 64 : cj[j];
    int idx = (t0 > 0) ? (sj[j] + (lane < t0 ? lane : t0 - 1)) : 0;
    med[j] = edges[idx];
  }

  const unsigned short* tbh = tx1h + PASS * 256 + lane * 4;
  for (int j = 0; j < 4; ++j) {
    float acc4[4];
#pragma unroll
    for (int q = 0; q < 4; ++q) acc4[q] = 0.0f;
    if (cj[j] > 0)
      gather_group_h(tbh, edges, sj[j], sj[j] + cj[j], lane, med[j], acc4);
    us4 o;
#pragma unroll
    for (int q = 0; q < 4; ++q) o[q] = f2bf(acc4[q]);
    *(us4*)&P[j * 4 + (lane >> 4)][(lane & 15) * 4] = o;
  }

  f4v acc[4];
#pragma unroll
  for (int nt = 0; nt < 4; ++nt) acc[nt] = (f4v){0.f, 0.f, 0.f, 0.f};

  int am = lane & 15, aq = (lane >> 4) * 8;
  int an = n0 + (am >> 2);
  int ab = PASS * 4 + (am & 3);
#pragma unroll
  for (int ks = 0; ks < 6; ++ks) {
    s8v a0;
    if (ks < 2) {
      a0 = __builtin_nontemporal_load(
          (const s8v*)&xh[(size_t)an * 512 + ab * 64 + ks * 32 + aq]);
    } else if (ks < 4) {
      a0 = *(const s8v*)&tx1h[(size_t)an * 512 + ab * 64 + (ks - 2) * 32 + aq];
    } else {
      a0 = *(const s8v*)&P[am][(ks - 4) * 32 + aq];
    }
#pragma unroll
    for (int nt = 0; nt < 4; ++nt) {
      s8v b = *(const s8v*)&pack[(((size_t)(ks * 4 + nt) * 64) + lane) * 8];
      acc[nt] = __builtin_amdgcn_mfma_f32_16x16x32_bf16(a0, b, acc[nt], 0, 0, 0);
    }
  }

  float bv[4];
#pragma unroll
  for (int nt = 0; nt < 4; ++nt) bv[nt] = bias[nt * 16 + (lane & 15)];
#pragma unroll
  for (int r = 0; r < 4; ++r) {
    int rl = (lane >> 4) * 4 + r;
    int n = n0 + (rl >> 2);
    int b = PASS * 4 + (rl & 3);
    float* orow = &out[((size_t)b * NN + n) * 64 + (lane & 15)];
#pragma unroll
    for (int nt = 0; nt < 4; ++nt)
      __builtin_nontemporal_store(acc[nt][r] + bv[nt], &orow[nt * 16]);
  }
}

// ---- fallback fp32 kernels (small-ws tiers) --------------------------------
__global__ __launch_bounds__(256) void cheb_prop(
    const float* __restrict__ tin, float* __restrict__ tout,
    const int* __restrict__ rowptr, const int* __restrict__ cnt,
    const int2* __restrict__ edges, int nwaves) {
  int wid = (blockIdx.x << 2) + (threadIdx.x >> 6);
  if (wid >= nwaves) return;
  int lane = threadIdx.x & 63;
  int b = wid / NN;
  int n = wid - b * NN;
  int s = rowptr[n];
  int e = s + cnt[n];
  const float* base = tin + (size_t)b * NN * NC;
  float acc = 0.0f;
  for (int j = s; j < e; ++j) {
    int2 ed = edges[j];
    acc += __int_as_float(ed.y) * base[(size_t)ed.x * NC + lane];
  }
  tout[((size_t)b * NN + n) * NC + lane] = acc;
}

__global__ __launch_bounds__(256) void cheb_gemm2(
    const float* __restrict__ x, const float* __restrict__ tx1,
    const float* ptx1, const float* __restrict__ wc,
    const float* __restrict__ bias, float* out, int nrows) {
  __shared__ float At[128][64];
  __shared__ float Ws[64][64];
  int tid = threadIdx.x;
  int tx = tid & 15;
  int ty = tid >> 4;
  long row0 = (long)blockIdx.x * 128;
  int sk4 = (tid & 15) * 4;
  int srb = tid >> 4;
  const float* sp[3] = {x, tx1, ptx1};
  float4 pa[8], pw[4];
  auto fetch = [&](int ch) {
    const float* s0 = sp[ch];
#pragma unroll
    for (int rr = 0; rr < 8; ++rr) {
      int roff = srb + rr * 16;
      if (row0 + roff < nrows)
        pa[rr] = *(const float4*)&s0[(size_t)(row0 + roff) * NC + sk4];
      else
        pa[rr] = make_float4(0.f, 0.f, 0.f, 0.f);
    }
#pragma unroll
    for (int ww = 0; ww < 4; ++ww) {
      int e4 = tid + 256 * ww;
      pw[ww] = *(const float4*)&wc[ch * 4096 + (e4 >> 4) * 64 + (e4 & 15) * 4];
    }
  };
  auto commit = [&]() {
#pragma unroll
    for (int rr = 0; rr < 8; ++rr)
      *(float4*)&At[srb + rr * 16][sk4] = pa[rr];
#pragma unroll
    for (int ww = 0; ww < 4; ++ww) {
      int e4 = tid + 256 * ww;
      *(float4*)&Ws[e4 >> 4][(e4 & 15) * 4] = pw[ww];
    }
  };
  float4 acc[8];
#pragma unroll
  for (int i = 0; i < 8; ++i) acc[i] = make_float4(0.f, 0.f, 0.f, 0.f);
  fetch(0);
  commit();
  for (int ch = 0; ch < 3; ++ch) {
    __syncthreads();
    if (ch < 2) fetch(ch + 1);
#pragma unroll 4
    for (int k4 = 0; k4 < 16; ++k4) {
      float4 w0 = *(float4*)&Ws[k4 * 4 + 0][tx * 4];
      float4 w1 = *(float4*)&Ws[k4 * 4 + 1][tx * 4];
      float4 w2 = *(float4*)&Ws[k4 * 4 + 2][tx * 4];
      float4 w3 = *(float4*)&Ws[k4 * 4 + 3][tx * 4];
#pragma unroll
      for (int i = 0; i < 8; ++i) {
        float4 a = *(float4*)&At[ty * 8 + i][k4 * 4];
        fma4(acc[i], a.x, w0);
        fma4(acc[i], a.y, w1);
        fma4(acc[i], a.z, w2);
        fma4(acc[i], a.w, w3);
      }
    }
    __syncthreads();
    if (ch < 2) commit();
  }
  float4 bb4 = *(const float4*)&bias[tx * 4];
#pragma unroll
  for (int i = 0; i < 8; ++i) {
    long r = row0 + ty * 8 + i;
    if (r >= nrows) continue;
    float4 o = make_float4(acc[i].x + bb4.x, acc[i].y + bb4.y,
                           acc[i].z + bb4.z, acc[i].w + bb4.w);
    *(float4*)&out[(size_t)r * NC + tx * 4] = o;
  }
}

extern "C" void kernel_launch(void* const* d_in, const int* in_sizes, int n_in,
                              void* d_out, int out_size, void* d_ws, size_t ws_size,
                              hipStream_t stream) {
  (void)in_sizes; (void)n_in; (void)out_size;
  const float* x    = (const float*)d_in[0];
  const float* w    = (const float*)d_in[1];
  const float* bias = (const float*)d_in[2];
  const int*   ei   = (const int*)d_in[3];
  float* out = (float*)d_out;
  char* ws = (char*)d_ws;

  size_t off = 0;
  auto alloc = [&](size_t bytes) -> void* {
    void* p = (void*)(ws + off);
    off = (off + bytes + 255) & ~(size_t)255;
    return p;
  };
  int* cnt      = (int*)alloc((size_t)(NN + 1) * sizeof(int));
  int* total    = cnt + NN;
  int* rowptr   = (int*)alloc((size_t)NN * sizeof(int));
  int* cur      = (int*)alloc((size_t)NN * sizeof(int));
  float* dinv   = (float*)alloc((size_t)NN * sizeof(float));
  int2* edges   = (int2*)alloc((size_t)NE * sizeof(int2));
  float* wcb    = (float*)alloc((size_t)3 * NC * NC * sizeof(float));
  unsigned short* pack = (unsigned short*)alloc((size_t)6 * 4 * 64 * 8 * sizeof(unsigned short));
  size_t small_end = off;

  const size_t fieldHB = (size_t)NN * 512 * sizeof(unsigned short);  // 51.2 MB
  const size_t perbB   = (size_t)NN * NC * sizeof(float);            // 12.8 MB

  if (ws_size >= small_end + 2 * fieldHB + 256) {
    // Tier A: bf16 pipeline; 7 dispatches (pre, count, offsets, scatter,
    // prop1h, fusedh x2) - best-known configuration (R6/R7 ~370 us)
    unsigned short* xh   = (unsigned short*)alloc(fieldHB);
    unsigned short* tx1h = (unsigned short*)alloc(fieldHB);
    cheb_pre<<<PRE_CONV_BLK + PRE_ZERO_BLK + 48, 256, 0, stream>>>(
        x, xh, w, pack, cnt);
    cheb_count  <<<(NE + 255) / 256, 256, 0, stream>>>(ei, cnt);
    cheb_offsets<<<(NN + 255) / 256, 256, 0, stream>>>(cnt, dinv, rowptr, cur, total);
    cheb_scatter<<<(NE + 255) / 256, 256, 0, stream>>>(ei, dinv, cur, edges);
    cheb_prop1h <<<NN / 4, 256, 0, stream>>>(xh, tx1h, rowptr, cnt, edges);
    cheb_fusedh<0><<<NN / 16, 256, 0, stream>>>(
        xh, tx1h, rowptr, cnt, edges, pack, bias, out);
    cheb_fusedh<1><<<NN / 16, 256, 0, stream>>>(
        xh, tx1h, rowptr, cnt, edges, pack, bias, out);
  } else if (ws_size >= small_end + 2 * perbB + 256) {
    // Tier B: per-batch fp32 fallback
    hipMemsetAsync(cnt, 0, (NN + 1) * sizeof(int), stream);
    cheb_count  <<<(NE + 255) / 256, 256, 0, stream>>>(ei, cnt);
    cheb_offsets<<<(NN + 255) / 256, 256, 0, stream>>>(cnt, dinv, rowptr, cur, total);
    cheb_scatter<<<(NE + 255) / 256, 256, 0, stream>>>(ei, dinv, cur, edges);
    cheb_wc<<<(NC * NC + 255) / 256, 256, 0, stream>>>(w, wcb);
    float* tx1b  = (float*)alloc(perbB);
    float* ptx1b = (float*)alloc(perbB);
    for (int b = 0; b < NB; ++b) {
      const float* xb = x + (size_t)b * NN * NC;
      float* outb = out + (size_t)b * NN * NC;
      cheb_prop<<<(NN + 3) / 4, 256, 0, stream>>>(xb, tx1b, rowptr, cnt, edges, NN);
      cheb_prop<<<(NN + 3) / 4, 256, 0, stream>>>(tx1b, ptx1b, rowptr, cnt, edges, NN);
      cheb_gemm2<<<(NN + 127) / 128, 256, 0, stream>>>(
          xb, tx1b, ptx1b, wcb, bias, outb, NN);
    }
  } else {
    // Tier C: per-batch fp32, ptx1 via out slice
    hipMemsetAsync(cnt, 0, (NN + 1) * sizeof(int), stream);
    cheb_count  <<<(NE + 255) / 256, 256, 0, stream>>>(ei, cnt);
    cheb_offsets<<<(NN + 255) / 256, 256, 0, stream>>>(cnt, dinv, rowptr, cur, total);
    cheb_scatter<<<(NE + 255) / 256, 256, 0, stream>>>(ei, dinv, cur, edges);
    cheb_wc<<<(NC * NC + 255) / 256, 256, 0, stream>>>(w, wcb);
    float* tx1b = (float*)alloc(perbB);
    for (int b = 0; b < NB; ++b) {
      const float* xb = x + (size_t)b * NN * NC;
      float* outb = out + (size_t)b * NN * NC;
      cheb_prop<<<(NN + 3) / 4, 256, 0, stream>>>(xb, tx1b, rowptr, cnt, edges, NN);
      cheb_prop<<<(NN + 3) / 4, 256, 0, stream>>>(tx1b, outb, rowptr, cnt, edges, NN);
      cheb_gemm2<<<(NN + 127) / 128, 256, 0, stream>>>(
          xb, tx1b, outb, wcb, bias, outb, NN);
    }
  }
}